// Round 1
// baseline (174.479 us; speedup 1.0000x reference)
//
#include <hip/hip_runtime.h>
#include <hip/hip_bf16.h>

// Conv2dWithLoRA: out = conv3x3(x, W_eff) + b, where W_eff = W + 2.0 * B@A.
// LoRA folded into weights -> single implicit-GEMM conv, bf16 MFMA, fp32 accum.
// M = 16*64*64 = 65536 pixels, N = 256 outs, K = 128*9 = 1152.

#define CIN   128
#define COUT  256
#define HIMG  64
#define WIMG  64
#define NBAT  16
#define HPAD  66
#define WPAD  66

typedef __bf16 bf16x8 __attribute__((ext_vector_type(8)));
typedef float f32x4 __attribute__((ext_vector_type(4)));

#define XPAD_ELEMS ((size_t)NBAT * HPAD * WPAD * CIN)   // 8,921,088
#define XPAD_BYTES (XPAD_ELEMS * 2)                      // 17,842,176
#define WT_ELEMS   ((size_t)9 * COUT * CIN)              // 294,912
#define WS_NEED    (XPAD_BYTES + WT_ELEMS * 2)

typedef __attribute__((address_space(1))) void gvoid;
typedef __attribute__((address_space(3))) void lvoid;

__device__ __forceinline__ void load_lds16(const void* g, void* l) {
    // async global->LDS, 16B per lane; LDS dest = wave-uniform base + lane*16
    __builtin_amdgcn_global_load_lds((gvoid*)g, (lvoid*)l, 16, 0, 0);
}

// ---------------------------------------------------------------------------
// Pre-kernel 1: W_eff = W + 2*B@A, cast bf16, layout Wt[tap][o][c] (c contig)
// grid: 294912/256 = 1152 blocks
__global__ void prep_w(const float* __restrict__ W, const float* __restrict__ lA,
                       const float* __restrict__ lB, __hip_bfloat16* __restrict__ Wt) {
    int idx = blockIdx.x * 256 + threadIdx.x;          // (tap*256 + o)*128 + c
    int c   = idx & 127;
    int o   = (idx >> 7) & 255;
    int tap = idx >> 15;                               // 0..8
    float acc = W[(o * 128 + c) * 9 + tap];
    float s = 0.f;
#pragma unroll
    for (int r = 0; r < 8; ++r)
        s += lB[o * 8 + r] * lA[r * 1152 + c * 9 + tap];
    acc += 2.0f * s;
    Wt[idx] = __float2bfloat16(acc);
}

// ---------------------------------------------------------------------------
// Pre-kernel 2: NCHW fp32 -> NHWC bf16 with +1 zero halo (halo via memset).
// One block per (n, input row h). LDS transpose keeps both sides coalesced.
__global__ void pad_x(const float* __restrict__ x, __hip_bfloat16* __restrict__ xpad) {
    __shared__ float tile[128][65];                    // +1 pad: conflict-free
    const int n = blockIdx.x >> 6;
    const int h = blockIdx.x & 63;
    const int t = threadIdx.x;
    const float* src = x + ((size_t)(n * 128) * 64 + h) * 64;   // x[n][0][h][0]
#pragma unroll
    for (int i = 0; i < 32; ++i) {
        int idx = i * 256 + t;
        int c = idx >> 6, w = idx & 63;
        tile[c][w] = src[(size_t)c * 4096 + w];        // coalesced along w
    }
    __syncthreads();
    __hip_bfloat16* dst = xpad + ((size_t)(n * 66 + h + 1) * 66 + 1) * 128; // [n][h+1][1][0]
#pragma unroll
    for (int i = 0; i < 16; ++i) {
        int idx = i * 256 + t;
        int cp = idx & 63, w = idx >> 6;
        int c = cp * 2;
        __hip_bfloat162 v;
        v.x = __float2bfloat16(tile[c][w]);
        v.y = __float2bfloat16(tile[c + 1][w]);
        *reinterpret_cast<__hip_bfloat162*>(dst + (size_t)w * 128 + c) = v;  // coalesced along c
    }
}

// ---------------------------------------------------------------------------
// Main kernel: implicit-GEMM conv. Tile 128(o) x 128(pix), BK=32.
// grid (512, 2): x = pixel tile (n, 2 rows), y = o half.
__global__ void __launch_bounds__(256) conv_mfma(
    const __bf16* __restrict__ xpad, const __bf16* __restrict__ Wt,
    const float* __restrict__ bias, float* __restrict__ out) {
    __shared__ __align__(16) __bf16 As[128 * 32];      // [o][k] k-contig
    __shared__ __align__(16) __bf16 Bs[128 * 32];      // [pix][k] k-contig

    const int tid  = threadIdx.x;
    const int wv   = tid >> 6;
    const int lane = tid & 63;

    const int pt    = blockIdx.x;                      // 0..511
    const int ob    = blockIdx.y;                      // 0..1
    const int n     = pt >> 5;
    const int h0    = (pt & 31) << 1;                  // 2 output rows per tile
    const int obase = ob << 7;

    // staging: e0/e1 = linear bf16 index in the 128x32 tile; 8 elems per lane
    const int e0 = tid * 8;                            // (wv*512 + lane*8)
    const int e1 = e0 + 2048;
    const int a0 = (obase + (e0 >> 5)) * 128 + (e0 & 31);
    const int a1 = (obase + (e1 >> 5)) * 128 + (e1 & 31);
    const int p0 = e0 >> 5, p1 = e1 >> 5;
    const int b0 = ((n * 66 + h0 + (p0 >> 6)) * 66 + (p0 & 63)) * 128 + (e0 & 31);
    const int b1 = ((n * 66 + h0 + (p1 >> 6)) * 66 + (p1 & 63)) * 128 + (e1 & 31);

    const int wo = (wv >> 1) << 6;                     // o offset of wave
    const int wp = (wv & 1) << 6;                      // pix offset of wave

    int a_off[4], b_off[4];
#pragma unroll
    for (int i = 0; i < 4; ++i) {
        a_off[i] = (wo + i * 16 + (lane & 15)) * 32 + (lane >> 4) * 8;
        b_off[i] = (wp + i * 16 + (lane & 15)) * 32 + (lane >> 4) * 8;
    }

    f32x4 acc[4][4] = {};

    for (int ks = 0; ks < 36; ++ks) {                  // 9 taps * 4 c-blocks
        const int tap = ks >> 2;
        const int cb  = ks & 3;
        const int kh  = tap / 3;
        const int kw  = tap - kh * 3;
        const int woff = tap * (COUT * CIN) + cb * 32;
        const int xoff = (kh * 66 + kw) * 128 + cb * 32;

        __syncthreads();                               // LDS free to overwrite
        load_lds16(Wt + woff + a0, &As[wv * 512]);
        load_lds16(Wt + woff + a1, &As[2048 + wv * 512]);
        load_lds16(xpad + xoff + b0, &Bs[wv * 512]);
        load_lds16(xpad + xoff + b1, &Bs[2048 + wv * 512]);
        __syncthreads();                               // staging complete

        bf16x8 af[4], bfr[4];
#pragma unroll
        for (int i = 0; i < 4; ++i) {
            af[i]  = *reinterpret_cast<const bf16x8*>(&As[a_off[i]]);
            bfr[i] = *reinterpret_cast<const bf16x8*>(&Bs[b_off[i]]);
        }
#pragma unroll
        for (int mi = 0; mi < 4; ++mi)
#pragma unroll
            for (int ni = 0; ni < 4; ++ni)
                acc[mi][ni] = __builtin_amdgcn_mfma_f32_16x16x32_bf16(
                    af[mi], bfr[ni], acc[mi][ni], 0, 0, 0);
    }

    // epilogue: D row=(lane>>4)*4+j (o), col=lane&15 (pix); + bias
    const int col  = lane & 15;
    const int orow = (lane >> 4) << 2;
    const int h    = h0 + (wv & 1);                    // wp=64 <-> second row
#pragma unroll
    for (int mi = 0; mi < 4; ++mi) {
        const int obm = obase + wo + mi * 16 + orow;
#pragma unroll
        for (int j = 0; j < 4; ++j) {
            const int o = obm + j;
            const float bj = bias[o];
            float* orow_ptr = out + (((size_t)n * 256 + o) * 64 + h) * 64;
#pragma unroll
            for (int ni = 0; ni < 4; ++ni)
                orow_ptr[ni * 16 + col] = acc[mi][ni][j] + bj;
        }
    }
}

// ---------------------------------------------------------------------------
// Fallback (only if workspace too small): naive fp32, correct but slow.
__global__ void conv_naive(const float* __restrict__ x, const float* __restrict__ W,
                           const float* __restrict__ b, const float* __restrict__ lA,
                           const float* __restrict__ lB, float* __restrict__ out) {
    int idx = blockIdx.x * 256 + threadIdx.x;          // ((n*256+o)*64+h)*64+w
    int w = idx & 63, h = (idx >> 6) & 63, o = (idx >> 12) & 255, n = idx >> 20;
    float acc = b[o];
    float hr[8] = {0, 0, 0, 0, 0, 0, 0, 0};
    for (int c = 0; c < 128; ++c)
        for (int kh = 0; kh < 3; ++kh) {
            int hy = h + kh - 1;
            if (hy < 0 || hy > 63) continue;
            for (int kw = 0; kw < 3; ++kw) {
                int wx = w + kw - 1;
                if (wx < 0 || wx > 63) continue;
                float xv = x[((n * 128 + c) * 64 + hy) * 64 + wx];
                int ka = c * 9 + kh * 3 + kw;
                acc += W[(o * 128 + c) * 9 + kh * 3 + kw] * xv;
#pragma unroll
                for (int r = 0; r < 8; ++r) hr[r] += lA[r * 1152 + ka] * xv;
            }
        }
    float ls = 0.f;
#pragma unroll
    for (int r = 0; r < 8; ++r) ls += lB[o * 8 + r] * hr[r];
    out[idx] = acc + 2.0f * ls;
}

// ---------------------------------------------------------------------------
extern "C" void kernel_launch(void* const* d_in, const int* in_sizes, int n_in,
                              void* d_out, int out_size, void* d_ws, size_t ws_size,
                              hipStream_t stream) {
    const float* x  = (const float*)d_in[0];
    const float* W  = (const float*)d_in[1];
    const float* b  = (const float*)d_in[2];
    const float* lA = (const float*)d_in[3];
    const float* lB = (const float*)d_in[4];
    float* out = (float*)d_out;

    if (ws_size < WS_NEED) {
        conv_naive<<<out_size / 256, 256, 0, stream>>>(x, W, b, lA, lB, out);
        return;
    }

    __hip_bfloat16* xpad = (__hip_bfloat16*)d_ws;
    __hip_bfloat16* Wt   = (__hip_bfloat16*)((char*)d_ws + XPAD_BYTES);

    hipMemsetAsync(xpad, 0, XPAD_BYTES, stream);       // zero halo
    pad_x<<<NBAT * 64, 256, 0, stream>>>(x, xpad);
    prep_w<<<(int)(WT_ELEMS / 256), 256, 0, stream>>>(W, lA, lB, Wt);
    conv_mfma<<<dim3(512, 2), 256, 0, stream>>>((const __bf16*)xpad, (const __bf16*)Wt, b, out);
}

// Round 3
// 144.447 us; speedup vs baseline: 1.2079x; 1.2079x over previous
//
#include <hip/hip_runtime.h>
#include <hip/hip_bf16.h>

// Conv2dWithLoRA: out = conv3x3(x, W_eff) + b, where W_eff = W + 2.0 * B@A.
// LoRA folded into weights -> single implicit-GEMM conv, bf16 MFMA, fp32 accum.
// M = 16*64*64 = 65536 pixels, N = 256 outs, K = 128*9 = 1152.
// R1: BK=64 + XOR-swizzled LDS (conflict-free ds_read_b128), halo fused into
//     pad_x (no memset launch), vectorized pad_x.
// R2: fix LDS row stride in fragment reads (<<7 -> <<6; As/Bs rows are 64
//     elements at BK=64, not 128). R1 read OOB -> NaN.

#define CIN   128
#define COUT  256
#define NBAT  16
#define HPAD  66
#define WPAD  66

typedef __bf16 bf16x8 __attribute__((ext_vector_type(8)));
typedef float f32x4 __attribute__((ext_vector_type(4)));

#define XPAD_ELEMS ((size_t)NBAT * HPAD * WPAD * CIN)   // 8,921,088
#define XPAD_BYTES (XPAD_ELEMS * 2)                      // 17,842,176
#define WT_ELEMS   ((size_t)9 * COUT * CIN)              // 294,912
#define WS_NEED    (XPAD_BYTES + WT_ELEMS * 2)

typedef __attribute__((address_space(1))) void gvoid;
typedef __attribute__((address_space(3))) void lvoid;

__device__ __forceinline__ void load_lds16(const void* g, void* l) {
    // async global->LDS, 16B per lane; LDS dest = wave-uniform base + lane*16
    __builtin_amdgcn_global_load_lds((gvoid*)g, (lvoid*)l, 16, 0, 0);
}

// ---------------------------------------------------------------------------
// Pre-kernel 1: W_eff = W + 2*B@A, cast bf16, layout Wt[tap][o][c] (c contig)
__global__ void prep_w(const float* __restrict__ W, const float* __restrict__ lA,
                       const float* __restrict__ lB, __hip_bfloat16* __restrict__ Wt) {
    int idx = blockIdx.x * 256 + threadIdx.x;          // (tap*256 + o)*128 + c
    int c   = idx & 127;
    int o   = (idx >> 7) & 255;
    int tap = idx >> 15;                               // 0..8
    float acc = W[(o * 128 + c) * 9 + tap];
    float s = 0.f;
#pragma unroll
    for (int r = 0; r < 8; ++r)
        s += lB[o * 8 + r] * lA[r * 1152 + c * 9 + tap];
    acc += 2.0f * s;
    Wt[idx] = __float2bfloat16(acc);
}

// ---------------------------------------------------------------------------
// Pre-kernel 2: NCHW fp32 -> NHWC bf16 with +1 zero halo (halo written here).
// One block per (n, input row h). float4 loads, bf16x8 (16B) stores.
__global__ void pad_x(const float* __restrict__ x, __bf16* __restrict__ xpad) {
    __shared__ float tile[128][66];                    // stride 66: 2-way reads
    const int n = blockIdx.x >> 6;
    const int h = blockIdx.x & 63;
    const int t = threadIdx.x;
    const float* src = x + (size_t)n * 128 * 4096 + (size_t)h * 64;
#pragma unroll
    for (int i = 0; i < 8; ++i) {                      // 2048 float4 total
        int g  = i * 256 + t;
        int c  = g >> 4;
        int w4 = (g & 15) * 4;
        const float4 v = *reinterpret_cast<const float4*>(src + (size_t)c * 4096 + w4);
        tile[c][w4 + 0] = v.x; tile[c][w4 + 1] = v.y;
        tile[c][w4 + 2] = v.z; tile[c][w4 + 3] = v.w;
    }
    __syncthreads();
    __bf16* dst = xpad + ((size_t)(n * 66 + h + 1) * 66 + 1) * 128;
#pragma unroll
    for (int i = 0; i < 4; ++i) {                      // 64w x 128c bf16 = 16KB
        int g  = i * 256 + t;
        int w  = g >> 4;
        int c0 = (g & 15) * 8;
        bf16x8 v;
#pragma unroll
        for (int j = 0; j < 8; ++j) v[j] = (__bf16)tile[c0 + j][w];
        *reinterpret_cast<bf16x8*>(dst + (size_t)w * 128 + c0) = v;
    }
    // halo: left/right pixel of this padded row
    bf16x8 z = {};
    __bf16* rowbase = xpad + (size_t)(n * 66 + h + 1) * 66 * 128;
    if (t < 32) {
        int ww = (t < 16) ? 0 : 65;
        int c0 = (t & 15) * 8;
        *reinterpret_cast<bf16x8*>(rowbase + (size_t)ww * 128 + c0) = z;
    }
    // top/bottom halo rows (full 66 px)
    if (h == 0 || h == 63) {
        __bf16* hrow = xpad + (size_t)(n * 66 + (h == 0 ? 0 : 65)) * 66 * 128;
        for (int i = t; i < 66 * 16; i += 256)
            *reinterpret_cast<bf16x8*>(hrow + (size_t)i * 8) = z;
    }
}

// ---------------------------------------------------------------------------
// Main kernel: implicit-GEMM conv. Tile 128(o) x 128(pix), BK=64, XOR swizzle.
// Physical LDS chunk (16B) of logical (row, q) lives at q^(row&7); the inverse
// permutation is applied on the per-lane GLOBAL address of global_load_lds
// (swz term below), so staging stays wave-uniform-base + lane*16.
// grid (512, 2): x = pixel tile (n, 2 rows), y = o half.
__global__ void __launch_bounds__(256) conv_mfma(
    const __bf16* __restrict__ xpad, const __bf16* __restrict__ Wt,
    const float* __restrict__ bias, float* __restrict__ out) {
    __shared__ __align__(16) __bf16 As[128 * 64];      // 16 KB, [row][8 chunks]
    __shared__ __align__(16) __bf16 Bs[128 * 64];      // 16 KB

    const int tid  = threadIdx.x;
    const int wv   = tid >> 6;
    const int lane = tid & 63;

    const int pt    = blockIdx.x;                      // 0..511
    const int ob    = blockIdx.y;                      // 0..1
    const int n     = pt >> 5;
    const int h0    = (pt & 31) << 1;                  // 2 output rows per tile
    const int obase = ob << 7;

    // per-lane swizzled source offset (elements), shared by A and B staging:
    // row-within-8 = lane>>3, logical chunk = (lane&7) ^ (lane>>3)
    const int swz = ((lane >> 3) << 7) + ((((lane & 7) ^ (lane >> 3)) & 7) << 3);

    const __bf16* aG[4];
    const __bf16* bG[4];
#pragma unroll
    for (int j = 0; j < 4; ++j) {
        const int row0 = wv * 32 + j * 8;              // first row of this instr
        aG[j] = Wt + (obase + row0) * 128 + swz;
        const int p0 = row0;                           // pixel id 0..127
        bG[j] = xpad + (((size_t)(n * 66 + h0 + (p0 >> 6)) * 66 + (p0 & 63)) * 128) + swz;
    }

    const int wo = (wv >> 1) << 6;                     // o offset of wave
    const int wp = (wv & 1) << 6;                      // pix offset of wave

    int arow[4], brow[4], qo[2];
#pragma unroll
    for (int i = 0; i < 4; ++i) {
        arow[i] = (wo + i * 16 + (lane & 15)) << 6;    // LDS row = 64 elems
        brow[i] = (wp + i * 16 + (lane & 15)) << 6;
    }
#pragma unroll
    for (int s = 0; s < 2; ++s)
        qo[s] = ((((lane >> 4) + s * 4) ^ (lane & 7)) << 3);

    f32x4 acc[4][4] = {};

#pragma unroll
    for (int tap = 0; tap < 9; ++tap) {
        const int kh = tap / 3, kw = tap % 3;
        const int aoff_t = tap * (COUT * CIN);
        const int boff_t = (kh * 66 + kw) * 128;
#pragma unroll
        for (int cb = 0; cb < 2; ++cb) {
            const int ao = aoff_t + cb * 64;
            const int bo = boff_t + cb * 64;
            __syncthreads();                           // LDS free to overwrite
#pragma unroll
            for (int j = 0; j < 4; ++j) {
                load_lds16(aG[j] + ao, &As[wv * 2048 + j * 512]);
                load_lds16(bG[j] + bo, &Bs[wv * 2048 + j * 512]);
            }
            __syncthreads();                           // staging complete
#pragma unroll
            for (int s = 0; s < 2; ++s) {
                bf16x8 af[4], bfr[4];
#pragma unroll
                for (int i = 0; i < 4; ++i) {
                    af[i]  = *reinterpret_cast<const bf16x8*>(&As[arow[i] + qo[s]]);
                    bfr[i] = *reinterpret_cast<const bf16x8*>(&Bs[brow[i] + qo[s]]);
                }
#pragma unroll
                for (int mi = 0; mi < 4; ++mi)
#pragma unroll
                    for (int ni = 0; ni < 4; ++ni)
                        acc[mi][ni] = __builtin_amdgcn_mfma_f32_16x16x32_bf16(
                            af[mi], bfr[ni], acc[mi][ni], 0, 0, 0);
            }
        }
    }

    // epilogue: D row=(lane>>4)*4+j (o), col=lane&15 (pix); + bias
    const int col  = lane & 15;
    const int orow = (lane >> 4) << 2;
    const int h    = h0 + (wv & 1);                    // wp=64 <-> second row
#pragma unroll
    for (int mi = 0; mi < 4; ++mi) {
        const int obm = obase + wo + mi * 16 + orow;
#pragma unroll
        for (int j = 0; j < 4; ++j) {
            const int o = obm + j;
            const float bj = bias[o];
            float* orow_ptr = out + (((size_t)n * 256 + o) * 64 + h) * 64;
#pragma unroll
            for (int ni = 0; ni < 4; ++ni)
                orow_ptr[ni * 16 + col] = acc[mi][ni][j] + bj;
        }
    }
}

// ---------------------------------------------------------------------------
// Fallback (only if workspace too small): naive fp32, correct but slow.
__global__ void conv_naive(const float* __restrict__ x, const float* __restrict__ W,
                           const float* __restrict__ b, const float* __restrict__ lA,
                           const float* __restrict__ lB, float* __restrict__ out) {
    int idx = blockIdx.x * 256 + threadIdx.x;          // ((n*256+o)*64+h)*64+w
    int w = idx & 63, h = (idx >> 6) & 63, o = (idx >> 12) & 255, n = idx >> 20;
    float acc = b[o];
    float hr[8] = {0, 0, 0, 0, 0, 0, 0, 0};
    for (int c = 0; c < 128; ++c)
        for (int kh = 0; kh < 3; ++kh) {
            int hy = h + kh - 1;
            if (hy < 0 || hy > 63) continue;
            for (int kw = 0; kw < 3; ++kw) {
                int wx = w + kw - 1;
                if (wx < 0 || wx > 63) continue;
                float xv = x[((n * 128 + c) * 64 + hy) * 64 + wx];
                int ka = c * 9 + kh * 3 + kw;
                acc += W[(o * 128 + c) * 9 + kh * 3 + kw] * xv;
#pragma unroll
                for (int r = 0; r < 8; ++r) hr[r] += lA[r * 1152 + ka] * xv;
            }
        }
    float ls = 0.f;
#pragma unroll
    for (int r = 0; r < 8; ++r) ls += lB[o * 8 + r] * hr[r];
    out[idx] = acc + 2.0f * ls;
}

// ---------------------------------------------------------------------------
extern "C" void kernel_launch(void* const* d_in, const int* in_sizes, int n_in,
                              void* d_out, int out_size, void* d_ws, size_t ws_size,
                              hipStream_t stream) {
    const float* x  = (const float*)d_in[0];
    const float* W  = (const float*)d_in[1];
    const float* b  = (const float*)d_in[2];
    const float* lA = (const float*)d_in[3];
    const float* lB = (const float*)d_in[4];
    float* out = (float*)d_out;

    if (ws_size < WS_NEED) {
        conv_naive<<<out_size / 256, 256, 0, stream>>>(x, W, b, lA, lB, out);
        return;
    }

    __bf16* xpad = (__bf16*)d_ws;
    __hip_bfloat16* Wt = (__hip_bfloat16*)((char*)d_ws + XPAD_BYTES);

    pad_x<<<NBAT * 64, 256, 0, stream>>>(x, xpad);
    prep_w<<<(int)(WT_ELEMS / 256), 256, 0, stream>>>(W, lA, lB, Wt);
    conv_mfma<<<dim3(512, 2), 256, 0, stream>>>(xpad, (const __bf16*)Wt, b, out);
}